// Round 1
// baseline (738.827 us; speedup 1.0000x reference)
//
#include <hip/hip_runtime.h>

#define EPS_BN 1e-5f

// ---------------------------------------------------------------- CSR build
__global__ __launch_bounds__(256) void hist_kernel(const int* __restrict__ dst,
                                                   int* __restrict__ cnt, int E) {
    int e = blockIdx.x * 256 + threadIdx.x;
    if (e < E) atomicAdd(&cnt[dst[e]], 1);
}

// Block-local scan + atomic block base. Slices stay contiguous per node since a
// node's counter lives entirely inside one block; global placement order is
// irrelevant for correctness of the gather.
__global__ __launch_bounds__(256) void scan_kernel(const int* __restrict__ cnt,
                                                   int* __restrict__ row_start,
                                                   int* __restrict__ cursor,
                                                   float* __restrict__ inv_deg,
                                                   int* __restrict__ counter, int N) {
    __shared__ int s[256];
    __shared__ int base_sh;
    int tid = threadIdx.x;
    int i0 = blockIdx.x * 1024 + tid * 4;
    int c[4], loc[4];
    int run = 0;
    for (int j = 0; j < 4; j++) {
        int i = i0 + j;
        c[j] = (i < N) ? cnt[i] : 0;
        loc[j] = run;
        run += c[j];
    }
    s[tid] = run;
    __syncthreads();
    for (int off = 1; off < 256; off <<= 1) {
        int t = (tid >= off) ? s[tid - off] : 0;
        __syncthreads();
        s[tid] += t;
        __syncthreads();
    }
    if (tid == 255) base_sh = atomicAdd(counter, s[255]);
    __syncthreads();
    int tbase = base_sh + s[tid] - run;  // exclusive prefix within block + base
    for (int j = 0; j < 4; j++) {
        int i = i0 + j;
        if (i < N) {
            int st = tbase + loc[j];
            row_start[i] = st;
            cursor[i] = st;
            inv_deg[i] = 1.0f / fmaxf((float)c[j], 1.0f);
        }
    }
}

__global__ __launch_bounds__(256) void fill_kernel(const int* __restrict__ src,
                                                   const int* __restrict__ dst,
                                                   int* __restrict__ cursor,
                                                   int* __restrict__ csr_src, int E) {
    int e = blockIdx.x * 256 + threadIdx.x;
    if (e < E) {
        int slot = atomicAdd(&cursor[dst[e]], 1);
        csr_src[slot] = src[e];
    }
}

// ---------------------------------------------------------------- GEMM (fp32)
// Y[N,M] = X[N,128] @ W[128,M].  K-chunked LDS staging, 4x4 register tile.
template <int M>
__global__ __launch_bounds__(256) void gemm_k128(const float* __restrict__ X,
                                                 const float* __restrict__ W,
                                                 float* __restrict__ Y, int N) {
    constexpr int K = 128;
    constexpr int KB = 64;          // K-chunk
    constexpr int CT = M / 4;       // column threads (float4 per thread)
    constexpr int RG = 256 / CT;    // row groups
    constexpr int RB = RG * 4;      // rows per block
    constexpr int XS = KB + 4;      // padded X tile stride (keeps 16B align, rotates banks)
    __shared__ float Wl[KB * M];
    __shared__ float Xl[RB * XS];

    const int tid = threadIdx.x;
    const int ct = tid % CT, rg = tid / CT;
    const int c0 = ct * 4, r0l = rg * 4;
    const int row0 = blockIdx.x * RB;

    float acc[4][4] = {{0.f, 0.f, 0.f, 0.f}, {0.f, 0.f, 0.f, 0.f},
                       {0.f, 0.f, 0.f, 0.f}, {0.f, 0.f, 0.f, 0.f}};

    for (int kb = 0; kb < K; kb += KB) {
        // stage W chunk (rows kb..kb+KB-1 are contiguous)
        const float4* W4 = (const float4*)(W + kb * M);
        float4* Wl4 = (float4*)Wl;
        for (int i = tid; i < KB * M / 4; i += 256) Wl4[i] = W4[i];
        // stage X tile chunk
        for (int i = tid; i < RB * (KB / 4); i += 256) {
            int r = i / (KB / 4), k4 = i % (KB / 4);
            int row = row0 + r;
            if (row >= N) row = N - 1;  // clamp (dup load, stores guarded)
            float4 v = *(const float4*)(X + (size_t)row * K + kb + k4 * 4);
            *(float4*)(&Xl[r * XS + k4 * 4]) = v;
        }
        __syncthreads();
#pragma unroll 8
        for (int k = 0; k < KB; k++) {
            float4 w = *(const float4*)&Wl[k * M + c0];
            float x0 = Xl[(r0l + 0) * XS + k];
            float x1 = Xl[(r0l + 1) * XS + k];
            float x2 = Xl[(r0l + 2) * XS + k];
            float x3 = Xl[(r0l + 3) * XS + k];
            acc[0][0] += x0 * w.x; acc[0][1] += x0 * w.y; acc[0][2] += x0 * w.z; acc[0][3] += x0 * w.w;
            acc[1][0] += x1 * w.x; acc[1][1] += x1 * w.y; acc[1][2] += x1 * w.z; acc[1][3] += x1 * w.w;
            acc[2][0] += x2 * w.x; acc[2][1] += x2 * w.y; acc[2][2] += x2 * w.z; acc[2][3] += x2 * w.w;
            acc[3][0] += x3 * w.x; acc[3][1] += x3 * w.y; acc[3][2] += x3 * w.z; acc[3][3] += x3 * w.w;
        }
        __syncthreads();
    }
    for (int i = 0; i < 4; i++) {
        int row = row0 + r0l + i;
        if (row < N) {
            float4 o = make_float4(acc[i][0], acc[i][1], acc[i][2], acc[i][3]);
            *(float4*)(&Y[(size_t)row * M + c0]) = o;
        }
    }
}

// ------------------------------------------------- gather-aggregate + combine
// out[n] = Hself[n] + inv_deg[n] * sum_{e in CSR(n)} Hn[csr_src[e]] + bias
// One wave per node. M=128: float2/lane. M=64: float/lane. In-place safe
// (Hself may == out): each wave reads its own row before writing it.
template <int M>
__global__ __launch_bounds__(256) void agg_combine(const float* Hself,
                                                   const float* __restrict__ Hn,
                                                   const int* __restrict__ row_start,
                                                   const int* __restrict__ cnt,
                                                   const float* __restrict__ inv_deg,
                                                   const int* __restrict__ csr_src,
                                                   const float* __restrict__ bias,
                                                   float* out, int N) {
    int wv = threadIdx.x >> 6, lane = threadIdx.x & 63;
    int n = blockIdx.x * 4 + wv;
    if (n >= N) return;
    int start = __builtin_amdgcn_readfirstlane(row_start[n]);
    int ec = __builtin_amdgcn_readfirstlane(cnt[n]);
    float inv = inv_deg[n];
    if constexpr (M == 128) {
        int c = lane * 2;
        float a0 = 0.f, a1 = 0.f;
        int e = 0;
        for (; e + 1 < ec; e += 2) {  // 2-wide unroll for MLP
            int s0 = __builtin_amdgcn_readfirstlane(csr_src[start + e]);
            int s1 = __builtin_amdgcn_readfirstlane(csr_src[start + e + 1]);
            float2 v0 = *(const float2*)&Hn[(size_t)s0 * M + c];
            float2 v1 = *(const float2*)&Hn[(size_t)s1 * M + c];
            a0 += v0.x + v1.x;
            a1 += v0.y + v1.y;
        }
        if (e < ec) {
            int s0 = __builtin_amdgcn_readfirstlane(csr_src[start + e]);
            float2 v0 = *(const float2*)&Hn[(size_t)s0 * M + c];
            a0 += v0.x;
            a1 += v0.y;
        }
        float2 hs = *(const float2*)&Hself[(size_t)n * M + c];
        float2 bb = *(const float2*)&bias[c];
        float2 o;
        o.x = hs.x + a0 * inv + bb.x;
        o.y = hs.y + a1 * inv + bb.y;
        *(float2*)&out[(size_t)n * M + c] = o;
    } else {
        int c = lane;
        float a = 0.f;
        int e = 0;
        for (; e + 1 < ec; e += 2) {
            int s0 = __builtin_amdgcn_readfirstlane(csr_src[start + e]);
            int s1 = __builtin_amdgcn_readfirstlane(csr_src[start + e + 1]);
            a += Hn[(size_t)s0 * M + c] + Hn[(size_t)s1 * M + c];
        }
        if (e < ec) {
            int s0 = __builtin_amdgcn_readfirstlane(csr_src[start + e]);
            a += Hn[(size_t)s0 * M + c];
        }
        out[(size_t)n * M + c] = Hself[(size_t)n * M + c] + a * inv + bias[c];
    }
}

// ---------------------------------------------------------------- BatchNorm
template <int M>
__global__ __launch_bounds__(256) void bn_stats(const float* __restrict__ H,
                                                float* __restrict__ sums, int N) {
    int tid = threadIdx.x;
    int c0 = (tid * 4) % M;  // constant per thread: 1024 % M == 0
    float s[4] = {0.f, 0.f, 0.f, 0.f}, q[4] = {0.f, 0.f, 0.f, 0.f};
    const float4* H4 = (const float4*)H;
    int total4 = N * (M / 4);
    for (int i = blockIdx.x * 256 + tid; i < total4; i += 256 * gridDim.x) {
        float4 v = H4[i];
        s[0] += v.x; q[0] += v.x * v.x;
        s[1] += v.y; q[1] += v.y * v.y;
        s[2] += v.z; q[2] += v.z * v.z;
        s[3] += v.w; q[3] += v.w * v.w;
    }
    __shared__ float red[256 * 8];
    for (int j = 0; j < 4; j++) {
        red[tid * 8 + j] = s[j];
        red[tid * 8 + 4 + j] = q[j];
    }
    __syncthreads();
    constexpr int GRP = M / 4;  // threads t, t+GRP, ... share c0
    if (tid < GRP) {
        float rs[8] = {0.f, 0.f, 0.f, 0.f, 0.f, 0.f, 0.f, 0.f};
        for (int p = tid; p < 256; p += GRP)
            for (int j = 0; j < 8; j++) rs[j] += red[p * 8 + j];
        for (int j = 0; j < 4; j++) {
            atomicAdd(&sums[c0 + j], rs[j]);
            atomicAdd(&sums[M + c0 + j], rs[4 + j]);
        }
    }
}

template <int M>
__global__ void bn_finalize(const float* __restrict__ sums, const float* __restrict__ gamma,
                            const float* __restrict__ beta, float* __restrict__ ss,
                            float invN) {
    int c = threadIdx.x;
    if (c < M) {
        float mu = sums[c] * invN;
        float var = sums[M + c] * invN - mu * mu;
        float sc = gamma[c] * rsqrtf(var + EPS_BN);
        ss[c] = sc;
        ss[M + c] = beta[c] - mu * sc;
    }
}

template <int M, bool RELU>
__global__ __launch_bounds__(256) void bn_apply(float* H, const float* __restrict__ ss,
                                                int N) {
    int total4 = N * (M / 4);
    float4* H4 = (float4*)H;
    for (int i = blockIdx.x * 256 + threadIdx.x; i < total4; i += 256 * gridDim.x) {
        int c0 = (i * 4) % M;
        float4 v = H4[i];
        float4 sc = *(const float4*)&ss[c0];
        float4 sh = *(const float4*)&ss[M + c0];
        v.x = v.x * sc.x + sh.x;
        v.y = v.y * sc.y + sh.y;
        v.z = v.z * sc.z + sh.z;
        v.w = v.w * sc.w + sh.w;
        if (RELU) {
            v.x = fmaxf(v.x, 0.f);
            v.y = fmaxf(v.y, 0.f);
            v.z = fmaxf(v.z, 0.f);
            v.w = fmaxf(v.w, 0.f);
        }
        H4[i] = v;
    }
}

// ---------------------------------------------------------------- launch
extern "C" void kernel_launch(void* const* d_in, const int* in_sizes, int n_in,
                              void* d_out, int out_size, void* d_ws, size_t ws_size,
                              hipStream_t stream) {
    const float* X = (const float*)d_in[0];
    const int* src = (const int*)d_in[1];
    const int* dst = (const int*)d_in[2];
    const float* Wself1 = (const float*)d_in[3];
    const float* Wneigh1 = (const float*)d_in[4];
    const float* b1 = (const float*)d_in[5];
    const float* g1 = (const float*)d_in[6];
    const float* be1 = (const float*)d_in[7];
    const float* Wself2 = (const float*)d_in[8];
    const float* Wneigh2 = (const float*)d_in[9];
    const float* b2 = (const float*)d_in[10];
    const float* g2 = (const float*)d_in[11];
    const float* be2 = (const float*)d_in[12];
    float* out = (float*)d_out;

    const int N = in_sizes[0] / 128;
    const int E = in_sizes[1];

    // workspace carve-up (zeroed region first, single memset)
    char* p = (char*)d_ws;
    auto carve = [&](size_t bytes) {
        char* r = p;
        p += (bytes + 255) & ~(size_t)255;
        return r;
    };
    int* cnt = (int*)carve((size_t)N * 4);
    int* counter = (int*)carve(4);
    float* sums1 = (float*)carve(256 * 4);
    float* sums2 = (float*)carve(128 * 4);
    size_t zero_bytes = (size_t)(p - (char*)d_ws);
    int* row_start = (int*)carve((size_t)N * 4);
    int* cursor = (int*)carve((size_t)N * 4);
    float* inv_deg = (float*)carve((size_t)N * 4);
    int* csr_src = (int*)carve((size_t)E * 4);
    float* ss1 = (float*)carve(256 * 4);
    float* ss2 = (float*)carve(128 * 4);
    float* bufA = (float*)carve((size_t)N * 128 * 4);
    float* bufB = (float*)carve((size_t)N * 128 * 4);

    hipMemsetAsync(d_ws, 0, zero_bytes, stream);

    int egrid = (E + 255) / 256;
    hist_kernel<<<egrid, 256, 0, stream>>>(dst, cnt, E);
    scan_kernel<<<(N + 1023) / 1024, 256, 0, stream>>>(cnt, row_start, cursor, inv_deg,
                                                       counter, N);
    fill_kernel<<<egrid, 256, 0, stream>>>(src, dst, cursor, csr_src, E);

    // ---- layer 1 (128 -> 128)
    gemm_k128<128><<<(N + 31) / 32, 256, 0, stream>>>(X, Wself1, bufA, N);
    gemm_k128<128><<<(N + 31) / 32, 256, 0, stream>>>(X, Wneigh1, bufB, N);
    agg_combine<128><<<(N + 3) / 4, 256, 0, stream>>>(bufA, bufB, row_start, cnt, inv_deg,
                                                      csr_src, b1, bufA, N);
    bn_stats<128><<<256, 256, 0, stream>>>(bufA, sums1, N);
    bn_finalize<128><<<1, 128, 0, stream>>>(sums1, g1, be1, ss1, 1.0f / (float)N);
    bn_apply<128, true><<<2048, 256, 0, stream>>>(bufA, ss1, N);

    // ---- layer 2 (128 -> 64), project-then-aggregate halves gather width
    gemm_k128<64><<<(N + 63) / 64, 256, 0, stream>>>(bufA, Wself2, out, N);
    gemm_k128<64><<<(N + 63) / 64, 256, 0, stream>>>(bufA, Wneigh2, bufB, N);
    agg_combine<64><<<(N + 3) / 4, 256, 0, stream>>>(out, bufB, row_start, cnt, inv_deg,
                                                     csr_src, b2, out, N);
    bn_stats<64><<<256, 256, 0, stream>>>(out, sums2, N);
    bn_finalize<64><<<1, 64, 0, stream>>>(sums2, g2, be2, ss2, 1.0f / (float)N);
    bn_apply<64, false><<<2048, 256, 0, stream>>>(out, ss2, N);
}

// Round 2
// 589.729 us; speedup vs baseline: 1.2528x; 1.2528x over previous
//
#include <hip/hip_runtime.h>

#define EPS_BN 1e-5f

typedef __attribute__((ext_vector_type(8))) short short8;
typedef __attribute__((ext_vector_type(4))) float f32x4;

__device__ __forceinline__ unsigned short f2bf(float x) {
    unsigned int u = __float_as_uint(x);
    u += 0x7fffu + ((u >> 16) & 1u);
    return (unsigned short)(u >> 16);
}
__device__ __forceinline__ float bf2f(unsigned short h) {
    return __uint_as_float(((unsigned int)h) << 16);
}

// ---------------------------------------------------------------- CSR build
__global__ __launch_bounds__(256) void hist_kernel(const int* __restrict__ dst,
                                                   int* __restrict__ cnt, int E) {
    int e = blockIdx.x * 256 + threadIdx.x;
    if (e < E) atomicAdd(&cnt[dst[e]], 1);
}

__global__ __launch_bounds__(256) void scan_kernel(const int* __restrict__ cnt,
                                                   int* __restrict__ row_start,
                                                   int* __restrict__ cursor,
                                                   float* __restrict__ inv_deg,
                                                   int* __restrict__ counter, int N) {
    __shared__ int s[256];
    __shared__ int base_sh;
    int tid = threadIdx.x;
    int i0 = blockIdx.x * 1024 + tid * 4;
    int c[4], loc[4];
    int run = 0;
    for (int j = 0; j < 4; j++) {
        int i = i0 + j;
        c[j] = (i < N) ? cnt[i] : 0;
        loc[j] = run;
        run += c[j];
    }
    s[tid] = run;
    __syncthreads();
    for (int off = 1; off < 256; off <<= 1) {
        int t = (tid >= off) ? s[tid - off] : 0;
        __syncthreads();
        s[tid] += t;
        __syncthreads();
    }
    if (tid == 255) base_sh = atomicAdd(counter, s[255]);
    __syncthreads();
    int tbase = base_sh + s[tid] - run;
    for (int j = 0; j < 4; j++) {
        int i = i0 + j;
        if (i < N) {
            int st = tbase + loc[j];
            row_start[i] = st;
            cursor[i] = st;
            inv_deg[i] = 1.0f / fmaxf((float)c[j], 1.0f);
        }
    }
}

__global__ __launch_bounds__(256) void fill_kernel(const int* __restrict__ src,
                                                   const int* __restrict__ dst,
                                                   int* __restrict__ cursor,
                                                   int* __restrict__ csr_src, int E) {
    int e = blockIdx.x * 256 + threadIdx.x;
    if (e < E) {
        int slot = atomicAdd(&cursor[dst[e]], 1);
        csr_src[slot] = src[e];
    }
}

// ---------------------------------------------------------------- conversions
__global__ __launch_bounds__(256) void cvt_x(const float* __restrict__ X,
                                             unsigned short* __restrict__ Xb, int total4) {
    const float4* X4 = (const float4*)X;
    for (int i = blockIdx.x * 256 + threadIdx.x; i < total4; i += 256 * gridDim.x) {
        float4 v = X4[i];
        ushort4 o;
        o.x = f2bf(v.x); o.y = f2bf(v.y); o.z = f2bf(v.z); o.w = f2bf(v.w);
        *(ushort4*)&Xb[(size_t)i * 4] = o;
    }
}

// Pre-swizzle W into MFMA B-fragment order so GEMM LDS staging is a flat copy.
// Fragment order: idx = ((kk*NCT + c)*64 + L)*8 + j maps to element
//   k = kk*32 + (L>>4)*8 + j, col = c*16 + (L&15).
__global__ __launch_bounds__(256) void cvt_w(const float* __restrict__ Ws1,
                                             const float* __restrict__ Wn1,
                                             const float* __restrict__ Ws2,
                                             const float* __restrict__ Wn2,
                                             unsigned short* __restrict__ W1f,
                                             unsigned short* __restrict__ W2f) {
    int i = blockIdx.x * 256 + threadIdx.x;
    if (i < 128 * 256) {  // W1: MT=256, NCT=16
        int j = i & 7, L = (i >> 3) & 63, c = (i >> 9) & 15, kk = i >> 13;
        int k = kk * 32 + (L >> 4) * 8 + j;
        int col = c * 16 + (L & 15);
        float v = (col < 128) ? Ws1[k * 128 + col] : Wn1[k * 128 + (col - 128)];
        W1f[i] = f2bf(v);
    } else {
        int idx = i - 128 * 256;
        if (idx < 128 * 128) {  // W2: MT=128, NCT=8
            int j = idx & 7, L = (idx >> 3) & 63, c = (idx >> 9) & 7, kk = idx >> 12;
            int k = kk * 32 + (L >> 4) * 8 + j;
            int col = c * 16 + (L & 15);
            float v = (col < 64) ? Ws2[k * 64 + col] : Wn2[k * 64 + (col - 64)];
            W2f[idx] = f2bf(v);
        }
    }
}

// ---------------------------------------------------------------- dual GEMM (MFMA bf16)
// Y = Xb[N,128] @ Wcat[128,MT]; cols [0,MSELF) -> fp32 Yself, [MSELF,MT) -> bf16 Ynb.
// W stays whole in LDS (fragment order); A-frags stream from global; K-loop barrier-free.
template <int MT, int MSELF>
__global__ __launch_bounds__(256) void gemm_dual(const unsigned short* __restrict__ Xb,
                                                 const unsigned short* __restrict__ Wf,
                                                 float* __restrict__ Yself,
                                                 unsigned short* __restrict__ Ynb, int N) {
    constexpr int K = 128;
    constexpr int NCT = MT / 16;
    constexpr int KS = K / 32;
    constexpr int MNB = MT - MSELF;
    __shared__ unsigned short Bl[KS * NCT * 64 * 8];

    // flat copy, already fragment-ordered
    for (int i = threadIdx.x; i < KS * NCT * 64; i += 256)
        ((short8*)Bl)[i] = ((const short8*)Wf)[i];
    __syncthreads();

    int wv = threadIdx.x >> 6, lane = threadIdx.x & 63;
    int row0 = blockIdx.x * 64 + wv * 16;
    int m = lane & 15, quad = lane >> 4;
    int arow = row0 + m;
    if (arow >= N) arow = N - 1;
    const unsigned short* aptr = Xb + (size_t)arow * K + quad * 8;

    short8 afrag[KS];
#pragma unroll
    for (int kk = 0; kk < KS; kk++) afrag[kk] = *(const short8*)(aptr + kk * 32);

    f32x4 acc[NCT];
#pragma unroll
    for (int c = 0; c < NCT; c++)
        for (int j = 0; j < 4; j++) acc[c][j] = 0.f;

#pragma unroll
    for (int kk = 0; kk < KS; kk++) {
#pragma unroll
        for (int c = 0; c < NCT; c++) {
            short8 bfrag = *(const short8*)&Bl[((kk * NCT + c) * 64 + lane) * 8];
            acc[c] = __builtin_amdgcn_mfma_f32_16x16x32_bf16(afrag[kk], bfrag, acc[c], 0, 0, 0);
        }
    }

    // C/D layout: col = lane&15, row = quad*4 + reg  [m89/m91 verified]
#pragma unroll
    for (int c = 0; c < NCT; c++) {
        int colg = c * 16 + m;
#pragma unroll
        for (int r = 0; r < 4; r++) {
            int row = row0 + quad * 4 + r;
            if (row < N) {
                float v = acc[c][r];
                if (colg < MSELF)
                    Yself[(size_t)row * MSELF + colg] = v;
                else
                    Ynb[(size_t)row * MNB + (colg - MSELF)] = f2bf(v);
            }
        }
    }
}

// ------------------------------------------------- gather-aggregate + combine
// out[n] = Hself[n] + inv_deg[n]*sum_e bf16Table[csr_src[e]] + bias. One wave/node.
__global__ __launch_bounds__(256) void agg_bf128(const float* Hself,
                                                 const unsigned int* __restrict__ T,
                                                 const int* __restrict__ row_start,
                                                 const int* __restrict__ cnt,
                                                 const float* __restrict__ inv_deg,
                                                 const int* __restrict__ csr_src,
                                                 const float* __restrict__ bias,
                                                 float* out, int N) {
    int wv = threadIdx.x >> 6, lane = threadIdx.x & 63;
    int n = blockIdx.x * 4 + wv;
    if (n >= N) return;
    int start = row_start[n];
    int ec = cnt[n];
    float inv = inv_deg[n];
    float a0 = 0.f, a1 = 0.f;
    int e = 0;
    for (; e + 3 < ec; e += 4) {
        int s0 = csr_src[start + e];
        int s1 = csr_src[start + e + 1];
        int s2 = csr_src[start + e + 2];
        int s3 = csr_src[start + e + 3];
        unsigned v0 = T[(size_t)s0 * 64 + lane];
        unsigned v1 = T[(size_t)s1 * 64 + lane];
        unsigned v2 = T[(size_t)s2 * 64 + lane];
        unsigned v3 = T[(size_t)s3 * 64 + lane];
        a0 += __uint_as_float(v0 << 16) + __uint_as_float(v1 << 16) +
              __uint_as_float(v2 << 16) + __uint_as_float(v3 << 16);
        a1 += __uint_as_float(v0 & 0xffff0000u) + __uint_as_float(v1 & 0xffff0000u) +
              __uint_as_float(v2 & 0xffff0000u) + __uint_as_float(v3 & 0xffff0000u);
    }
    for (; e < ec; e++) {
        int s0 = csr_src[start + e];
        unsigned v0 = T[(size_t)s0 * 64 + lane];
        a0 += __uint_as_float(v0 << 16);
        a1 += __uint_as_float(v0 & 0xffff0000u);
    }
    int c = lane * 2;
    float2 hs = *(const float2*)&Hself[(size_t)n * 128 + c];
    float2 bb = *(const float2*)&bias[c];
    float2 o;
    o.x = hs.x + a0 * inv + bb.x;
    o.y = hs.y + a1 * inv + bb.y;
    *(float2*)&out[(size_t)n * 128 + c] = o;
}

__global__ __launch_bounds__(256) void agg_bf64(const float* Hself,
                                                const unsigned short* __restrict__ T,
                                                const int* __restrict__ row_start,
                                                const int* __restrict__ cnt,
                                                const float* __restrict__ inv_deg,
                                                const int* __restrict__ csr_src,
                                                const float* __restrict__ bias,
                                                float* out, int N) {
    int wv = threadIdx.x >> 6, lane = threadIdx.x & 63;
    int n = blockIdx.x * 4 + wv;
    if (n >= N) return;
    int start = row_start[n];
    int ec = cnt[n];
    float inv = inv_deg[n];
    float a = 0.f;
    int e = 0;
    for (; e + 3 < ec; e += 4) {
        int s0 = csr_src[start + e];
        int s1 = csr_src[start + e + 1];
        int s2 = csr_src[start + e + 2];
        int s3 = csr_src[start + e + 3];
        a += bf2f(T[(size_t)s0 * 64 + lane]) + bf2f(T[(size_t)s1 * 64 + lane]) +
             bf2f(T[(size_t)s2 * 64 + lane]) + bf2f(T[(size_t)s3 * 64 + lane]);
    }
    for (; e < ec; e++) a += bf2f(T[(size_t)csr_src[start + e] * 64 + lane]);
    out[(size_t)n * 64 + lane] = Hself[(size_t)n * 64 + lane] + a * inv + bias[lane];
}

// ---------------------------------------------------------------- BatchNorm
template <int M>
__global__ __launch_bounds__(256) void bn_stats(const float* __restrict__ H,
                                                float* __restrict__ sums, int N) {
    int tid = threadIdx.x;
    int c0 = (tid * 4) % M;
    float s[4] = {0.f, 0.f, 0.f, 0.f}, q[4] = {0.f, 0.f, 0.f, 0.f};
    const float4* H4 = (const float4*)H;
    int total4 = N * (M / 4);
    for (int i = blockIdx.x * 256 + tid; i < total4; i += 256 * gridDim.x) {
        float4 v = H4[i];
        s[0] += v.x; q[0] += v.x * v.x;
        s[1] += v.y; q[1] += v.y * v.y;
        s[2] += v.z; q[2] += v.z * v.z;
        s[3] += v.w; q[3] += v.w * v.w;
    }
    __shared__ float red[256 * 8];
    for (int j = 0; j < 4; j++) {
        red[tid * 8 + j] = s[j];
        red[tid * 8 + 4 + j] = q[j];
    }
    __syncthreads();
    constexpr int GRP = M / 4;
    if (tid < GRP) {
        float rs[8] = {0.f, 0.f, 0.f, 0.f, 0.f, 0.f, 0.f, 0.f};
        for (int p = tid; p < 256; p += GRP)
            for (int j = 0; j < 8; j++) rs[j] += red[p * 8 + j];
        for (int j = 0; j < 4; j++) {
            atomicAdd(&sums[c0 + j], rs[j]);
            atomicAdd(&sums[M + c0 + j], rs[4 + j]);
        }
    }
}

template <int M>
__global__ void bn_finalize(const float* __restrict__ sums, const float* __restrict__ gamma,
                            const float* __restrict__ beta, float* __restrict__ ss,
                            float invN) {
    int c = threadIdx.x;
    if (c < M) {
        float mu = sums[c] * invN;
        float var = sums[M + c] * invN - mu * mu;
        float sc = gamma[c] * rsqrtf(var + EPS_BN);
        ss[c] = sc;
        ss[M + c] = beta[c] - mu * sc;
    }
}

// layer-1 apply: fp32 in -> BN+ReLU -> bf16 out (feeds layer-2 GEMM)
__global__ __launch_bounds__(256) void bn_apply_bf128(const float* __restrict__ H,
                                                      const float* __restrict__ ss,
                                                      unsigned short* __restrict__ O, int N) {
    int total4 = N * 32;
    const float4* H4 = (const float4*)H;
    for (int i = blockIdx.x * 256 + threadIdx.x; i < total4; i += 256 * gridDim.x) {
        int c0 = (i * 4) & 127;
        float4 v = H4[i];
        float4 sc = *(const float4*)&ss[c0];
        float4 sh = *(const float4*)&ss[128 + c0];
        ushort4 o;
        o.x = f2bf(fmaxf(v.x * sc.x + sh.x, 0.f));
        o.y = f2bf(fmaxf(v.y * sc.y + sh.y, 0.f));
        o.z = f2bf(fmaxf(v.z * sc.z + sh.z, 0.f));
        o.w = f2bf(fmaxf(v.w * sc.w + sh.w, 0.f));
        *(ushort4*)&O[(size_t)i * 4] = o;
    }
}

// layer-2 apply: fp32 in-place, no ReLU
__global__ __launch_bounds__(256) void bn_apply_f64(float* H, const float* __restrict__ ss,
                                                    int N) {
    int total4 = N * 16;
    float4* H4 = (float4*)H;
    for (int i = blockIdx.x * 256 + threadIdx.x; i < total4; i += 256 * gridDim.x) {
        int c0 = (i * 4) & 63;
        float4 v = H4[i];
        float4 sc = *(const float4*)&ss[c0];
        float4 sh = *(const float4*)&ss[64 + c0];
        v.x = v.x * sc.x + sh.x;
        v.y = v.y * sc.y + sh.y;
        v.z = v.z * sc.z + sh.z;
        v.w = v.w * sc.w + sh.w;
        H4[i] = v;
    }
}

// ---------------------------------------------------------------- launch
extern "C" void kernel_launch(void* const* d_in, const int* in_sizes, int n_in,
                              void* d_out, int out_size, void* d_ws, size_t ws_size,
                              hipStream_t stream) {
    const float* X = (const float*)d_in[0];
    const int* src = (const int*)d_in[1];
    const int* dst = (const int*)d_in[2];
    const float* Wself1 = (const float*)d_in[3];
    const float* Wneigh1 = (const float*)d_in[4];
    const float* b1 = (const float*)d_in[5];
    const float* g1 = (const float*)d_in[6];
    const float* be1 = (const float*)d_in[7];
    const float* Wself2 = (const float*)d_in[8];
    const float* Wneigh2 = (const float*)d_in[9];
    const float* b2 = (const float*)d_in[10];
    const float* g2 = (const float*)d_in[11];
    const float* be2 = (const float*)d_in[12];
    float* out = (float*)d_out;

    const int N = in_sizes[0] / 128;
    const int E = in_sizes[1];

    char* p = (char*)d_ws;
    auto carve = [&](size_t bytes) {
        char* r = p;
        p += (bytes + 255) & ~(size_t)255;
        return r;
    };
    int* cnt = (int*)carve((size_t)N * 4);
    int* counter = (int*)carve(4);
    float* sums1 = (float*)carve(256 * 4);
    float* sums2 = (float*)carve(128 * 4);
    size_t zero_bytes = (size_t)(p - (char*)d_ws);
    int* row_start = (int*)carve((size_t)N * 4);
    int* cursor = (int*)carve((size_t)N * 4);
    float* inv_deg = (float*)carve((size_t)N * 4);
    int* csr_src = (int*)carve((size_t)E * 4);
    float* ss1 = (float*)carve(256 * 4);
    float* ss2 = (float*)carve(128 * 4);
    unsigned short* W1f = (unsigned short*)carve(128 * 256 * 2);
    unsigned short* W2f = (unsigned short*)carve(128 * 128 * 2);
    float* bufA = (float*)carve((size_t)N * 128 * 4);           // fp32 intermediate
    unsigned short* Xb = (unsigned short*)carve((size_t)N * 128 * 2);   // also h1b
    unsigned short* tab = (unsigned short*)carve((size_t)N * 128 * 2);  // tab1 (128) / tab2 (64)

    hipMemsetAsync(d_ws, 0, zero_bytes, stream);

    int egrid = (E + 255) / 256;
    cvt_x<<<2048, 256, 0, stream>>>(X, Xb, N * 32);
    cvt_w<<<192, 256, 0, stream>>>(Wself1, Wneigh1, Wself2, Wneigh2, W1f, W2f);
    hist_kernel<<<egrid, 256, 0, stream>>>(dst, cnt, E);
    scan_kernel<<<(N + 1023) / 1024, 256, 0, stream>>>(cnt, row_start, cursor, inv_deg,
                                                       counter, N);
    fill_kernel<<<egrid, 256, 0, stream>>>(src, dst, cursor, csr_src, E);

    int ggrid = (N + 63) / 64;
    // ---- layer 1 (128 -> 128): Yself fp32 -> bufA, Yneigh bf16 -> tab
    gemm_dual<256, 128><<<ggrid, 256, 0, stream>>>(Xb, W1f, bufA, tab, N);
    agg_bf128<<<(N + 3) / 4, 256, 0, stream>>>(bufA, (const unsigned int*)tab, row_start,
                                               cnt, inv_deg, csr_src, b1, bufA, N);
    bn_stats<128><<<256, 256, 0, stream>>>(bufA, sums1, N);
    bn_finalize<128><<<1, 128, 0, stream>>>(sums1, g1, be1, ss1, 1.0f / (float)N);
    bn_apply_bf128<<<2048, 256, 0, stream>>>(bufA, ss1, Xb, N);  // h1 bf16 overlays Xb

    // ---- layer 2 (128 -> 64): Yself fp32 -> out, Yneigh bf16 -> tab (reused)
    gemm_dual<128, 64><<<ggrid, 256, 0, stream>>>(Xb, W2f, out, tab, N);
    agg_bf64<<<(N + 3) / 4, 256, 0, stream>>>(out, tab, row_start, cnt, inv_deg, csr_src,
                                              b2, out, N);
    bn_stats<64><<<256, 256, 0, stream>>>(out, sums2, N);
    bn_finalize<64><<<1, 64, 0, stream>>>(sums2, g2, be2, ss2, 1.0f / (float)N);
    bn_apply_f64<<<2048, 256, 0, stream>>>(out, ss2, N);
}

// Round 3
// 523.595 us; speedup vs baseline: 1.4111x; 1.1263x over previous
//
#include <hip/hip_runtime.h>

#define EPS_BN 1e-5f
#define BINSHIFT 9
#define BINW 512
#define P_EPB 8192   // edges per block in count/scatter passes
#define LDS_CAP 10240

typedef __attribute__((ext_vector_type(8))) short short8;
typedef __attribute__((ext_vector_type(4))) float f32x4;

__device__ __forceinline__ unsigned short f2bf(float x) {
    unsigned int u = __float_as_uint(x);
    u += 0x7fffu + ((u >> 16) & 1u);
    return (unsigned short)(u >> 16);
}
__device__ __forceinline__ float bf2f(unsigned short h) {
    return __uint_as_float(((unsigned int)h) << 16);
}

// inclusive Hillis-Steele scan over a[0..511], 512 threads
__device__ __forceinline__ void scan512(int* a, int t) {
    for (int off = 1; off < 512; off <<= 1) {
        int v = (t >= off) ? a[t - off] : 0;
        __syncthreads();
        a[t] += v;
        __syncthreads();
    }
}

// ------------------------------------------------ prep: cvt_x | cvt_w | p1_count
__global__ __launch_bounds__(256) void prep_kernel(
    const float* __restrict__ X, unsigned short* __restrict__ Xb, int total4,
    const float* __restrict__ Ws1, const float* __restrict__ Wn1,
    const float* __restrict__ Ws2, const float* __restrict__ Wn2,
    unsigned short* __restrict__ W1f, unsigned short* __restrict__ W2f,
    const int* __restrict__ dst, int* __restrict__ counts, int E, int NB,
    int cvtB, int wB) {
    int tid = threadIdx.x;
    if (blockIdx.x < cvtB) {
        const float4* X4 = (const float4*)X;
        for (int i = blockIdx.x * 256 + tid; i < total4; i += 256 * cvtB) {
            float4 v = X4[i];
            ushort4 o;
            o.x = f2bf(v.x); o.y = f2bf(v.y); o.z = f2bf(v.z); o.w = f2bf(v.w);
            *(ushort4*)&Xb[(size_t)i * 4] = o;
        }
    } else if (blockIdx.x < cvtB + wB) {
        int i = (blockIdx.x - cvtB) * 256 + tid;
        if (i < 128 * 256) {  // W1: MT=256, NCT=16
            int j = i & 7, L = (i >> 3) & 63, c = (i >> 9) & 15, kk = i >> 13;
            int k = kk * 32 + (L >> 4) * 8 + j;
            int col = c * 16 + (L & 15);
            float v = (col < 128) ? Ws1[k * 128 + col] : Wn1[k * 128 + (col - 128)];
            W1f[i] = f2bf(v);
        } else {
            int idx = i - 128 * 256;
            if (idx < 128 * 128) {  // W2: MT=128, NCT=8
                int j = idx & 7, L = (idx >> 3) & 63, c = (idx >> 9) & 7, kk = idx >> 12;
                int k = kk * 32 + (L >> 4) * 8 + j;
                int col = c * 16 + (L & 15);
                float v = (col < 64) ? Ws2[k * 64 + col] : Wn2[k * 64 + (col - 64)];
                W2f[idx] = f2bf(v);
            }
        }
    } else {
        __shared__ int hist[512];
        int blk = blockIdx.x - cvtB - wB;
        int e0 = blk * P_EPB, e1 = min(e0 + P_EPB, E);
        for (int b = tid; b < 512; b += 256) hist[b] = 0;
        __syncthreads();
        for (int e = e0 + tid; e < e1; e += 256) atomicAdd(&hist[dst[e] >> BINSHIFT], 1);
        __syncthreads();
        for (int b = tid; b < NB; b += 256) counts[blk * NB + b] = hist[b];
    }
}

// ------------------------------------------------ p2: bin bases + segment bases
__global__ __launch_bounds__(512) void p2_scan(const int* __restrict__ counts,
                                               int* __restrict__ segbase,
                                               int* __restrict__ binBase, int NB, int NBLK) {
    __shared__ int tot[512];
    int t = threadIdx.x;
    int mytot = 0;
    if (t < NB)
        for (int blk = 0; blk < NBLK; blk++) mytot += counts[blk * NB + t];
    tot[t] = mytot;
    __syncthreads();
    scan512(tot, t);
    int excl = tot[t] - mytot;
    if (t < NB) binBase[t] = excl;
    if (t == NB) binBase[NB] = excl;  // == total E (tot beyond NB are 0-count)
    if (t < NB) {
        int run = excl;
        for (int blk = 0; blk < NBLK; blk++) {
            segbase[blk * NB + t] = run;
            run += counts[blk * NB + t];
        }
    }
}

// ------------------------------------------------ p3: LDS-binned scatter of pairs
__global__ __launch_bounds__(512) void p3_scatter(const int* __restrict__ src,
                                                  const int* __restrict__ dst,
                                                  const int* __restrict__ segbase,
                                                  uint2* __restrict__ pairs, int E, int NB) {
    __shared__ uint2 lp[P_EPB];
    __shared__ int hist[512];
    __shared__ int sBase[513];
    __shared__ int cursor[512];
    int t = threadIdx.x;
    int blk = blockIdx.x;
    int e0 = blk * P_EPB, e1 = min(e0 + P_EPB, E), m = e1 - e0;
    hist[t] = 0;
    __syncthreads();
    for (int e = e0 + t; e < e1; e += 512) atomicAdd(&hist[dst[e] >> BINSHIFT], 1);
    __syncthreads();
    int h = hist[t];
    scan512(hist, t);
    int excl = hist[t] - h;
    sBase[t] = excl;
    cursor[t] = excl;
    if (t == 0) sBase[512] = m;
    __syncthreads();
    for (int e = e0 + t; e < e1; e += 512) {
        int d = dst[e];
        int pos = atomicAdd(&cursor[d >> BINSHIFT], 1);
        lp[pos] = make_uint2((unsigned)src[e], (unsigned)d);
    }
    __syncthreads();
    for (int i = t; i < m; i += 512) {
        int lo = 0, hi = NB;  // largest bin with sBase[bin] <= i
        while (hi - lo > 1) {
            int mid = (lo + hi) >> 1;
            if (sBase[mid] <= i) lo = mid; else hi = mid;
        }
        pairs[segbase[blk * NB + lo] + (i - sBase[lo])] = lp[i];
    }
}

// ------------------------------------------------ p4: per-bin CSR finalize
__global__ __launch_bounds__(512) void p4_csr(const uint2* __restrict__ pairs,
                                              const int* __restrict__ binBase,
                                              int* __restrict__ row_start,
                                              int* __restrict__ cntg,
                                              float* __restrict__ inv_deg,
                                              int* __restrict__ csr_src, int N) {
    __shared__ int ncnt[512];
    __shared__ int cursor[512];
    __shared__ int lsrc[LDS_CAP];
    int t = threadIdx.x;
    int b = blockIdx.x;
    int e0 = binBase[b], e1 = binBase[b + 1], m = e1 - e0;
    int nbase = b << BINSHIFT;
    int nn = min(N - nbase, BINW);
    ncnt[t] = 0;
    __syncthreads();
    for (int i = e0 + t; i < e1; i += 512) atomicAdd(&ncnt[pairs[i].y - nbase], 1);
    __syncthreads();
    int c = ncnt[t];
    scan512(ncnt, t);
    int excl = ncnt[t] - c;
    if (t < nn) {
        int node = nbase + t;
        row_start[node] = e0 + excl;
        cntg[node] = c;
        inv_deg[node] = 1.0f / fmaxf((float)c, 1.0f);
    }
    cursor[t] = excl;
    __syncthreads();
    for (int i = e0 + t; i < e1; i += 512) {
        uint2 p = pairs[i];
        int pos = atomicAdd(&cursor[p.y - nbase], 1);
        if (pos < LDS_CAP) lsrc[pos] = (int)p.x;
    }
    __syncthreads();
    int mm = min(m, LDS_CAP);
    for (int i = t; i < mm; i += 512) csr_src[e0 + i] = lsrc[i];
}

// ---------------------------------------------------------------- dual GEMM (MFMA bf16)
template <int MT, int MSELF>
__global__ __launch_bounds__(256) void gemm_dual(const unsigned short* __restrict__ Xb,
                                                 const unsigned short* __restrict__ Wf,
                                                 float* __restrict__ Yself,
                                                 unsigned short* __restrict__ Ynb, int N) {
    constexpr int K = 128;
    constexpr int NCT = MT / 16;
    constexpr int KS = K / 32;
    constexpr int MNB = MT - MSELF;
    __shared__ unsigned short Bl[KS * NCT * 64 * 8];

    for (int i = threadIdx.x; i < KS * NCT * 64; i += 256)
        ((short8*)Bl)[i] = ((const short8*)Wf)[i];
    __syncthreads();

    int wv = threadIdx.x >> 6, lane = threadIdx.x & 63;
    int row0 = blockIdx.x * 64 + wv * 16;
    int m = lane & 15, quad = lane >> 4;
    int arow = row0 + m;
    if (arow >= N) arow = N - 1;
    const unsigned short* aptr = Xb + (size_t)arow * K + quad * 8;

    short8 afrag[KS];
#pragma unroll
    for (int kk = 0; kk < KS; kk++) afrag[kk] = *(const short8*)(aptr + kk * 32);

    f32x4 acc[NCT];
#pragma unroll
    for (int c = 0; c < NCT; c++)
        for (int j = 0; j < 4; j++) acc[c][j] = 0.f;

#pragma unroll
    for (int kk = 0; kk < KS; kk++) {
#pragma unroll
        for (int c = 0; c < NCT; c++) {
            short8 bfrag = *(const short8*)&Bl[((kk * NCT + c) * 64 + lane) * 8];
            acc[c] = __builtin_amdgcn_mfma_f32_16x16x32_bf16(afrag[kk], bfrag, acc[c], 0, 0, 0);
        }
    }

    // C/D layout: col = lane&15, row = quad*4 + reg
#pragma unroll
    for (int c = 0; c < NCT; c++) {
        int colg = c * 16 + m;
#pragma unroll
        for (int r = 0; r < 4; r++) {
            int row = row0 + quad * 4 + r;
            if (row < N) {
                float v = acc[c][r];
                if (colg < MSELF)
                    Yself[(size_t)row * MSELF + colg] = v;
                else
                    Ynb[(size_t)row * MNB + (colg - MSELF)] = f2bf(v);
            }
        }
    }
}

// ------------------------------------------------- gather-aggregate + combine
__global__ __launch_bounds__(256) void agg_bf128(const float* Hself,
                                                 const unsigned int* __restrict__ T,
                                                 const int* __restrict__ row_start,
                                                 const int* __restrict__ cnt,
                                                 const float* __restrict__ inv_deg,
                                                 const int* __restrict__ csr_src,
                                                 const float* __restrict__ bias,
                                                 float* out, int N) {
    int wv = threadIdx.x >> 6, lane = threadIdx.x & 63;
    int n = blockIdx.x * 4 + wv;
    if (n >= N) return;
    int start = row_start[n];
    int ec = cnt[n];
    float inv = inv_deg[n];
    float a0 = 0.f, a1 = 0.f;
    int e = 0;
    for (; e + 3 < ec; e += 4) {
        int s0 = csr_src[start + e];
        int s1 = csr_src[start + e + 1];
        int s2 = csr_src[start + e + 2];
        int s3 = csr_src[start + e + 3];
        unsigned v0 = T[(size_t)s0 * 64 + lane];
        unsigned v1 = T[(size_t)s1 * 64 + lane];
        unsigned v2 = T[(size_t)s2 * 64 + lane];
        unsigned v3 = T[(size_t)s3 * 64 + lane];
        a0 += __uint_as_float(v0 << 16) + __uint_as_float(v1 << 16) +
              __uint_as_float(v2 << 16) + __uint_as_float(v3 << 16);
        a1 += __uint_as_float(v0 & 0xffff0000u) + __uint_as_float(v1 & 0xffff0000u) +
              __uint_as_float(v2 & 0xffff0000u) + __uint_as_float(v3 & 0xffff0000u);
    }
    for (; e < ec; e++) {
        int s0 = csr_src[start + e];
        unsigned v0 = T[(size_t)s0 * 64 + lane];
        a0 += __uint_as_float(v0 << 16);
        a1 += __uint_as_float(v0 & 0xffff0000u);
    }
    int c = lane * 2;
    float2 hs = *(const float2*)&Hself[(size_t)n * 128 + c];
    float2 bb = *(const float2*)&bias[c];
    float2 o;
    o.x = hs.x + a0 * inv + bb.x;
    o.y = hs.y + a1 * inv + bb.y;
    *(float2*)&out[(size_t)n * 128 + c] = o;
}

__global__ __launch_bounds__(256) void agg_bf64(const float* Hself,
                                                const unsigned short* __restrict__ T,
                                                const int* __restrict__ row_start,
                                                const int* __restrict__ cnt,
                                                const float* __restrict__ inv_deg,
                                                const int* __restrict__ csr_src,
                                                const float* __restrict__ bias,
                                                float* out, int N) {
    int wv = threadIdx.x >> 6, lane = threadIdx.x & 63;
    int n = blockIdx.x * 4 + wv;
    if (n >= N) return;
    int start = row_start[n];
    int ec = cnt[n];
    float inv = inv_deg[n];
    float a = 0.f;
    int e = 0;
    for (; e + 3 < ec; e += 4) {
        int s0 = csr_src[start + e];
        int s1 = csr_src[start + e + 1];
        int s2 = csr_src[start + e + 2];
        int s3 = csr_src[start + e + 3];
        a += bf2f(T[(size_t)s0 * 64 + lane]) + bf2f(T[(size_t)s1 * 64 + lane]) +
             bf2f(T[(size_t)s2 * 64 + lane]) + bf2f(T[(size_t)s3 * 64 + lane]);
    }
    for (; e < ec; e++) a += bf2f(T[(size_t)csr_src[start + e] * 64 + lane]);
    out[(size_t)n * 64 + lane] = Hself[(size_t)n * 64 + lane] + a * inv + bias[lane];
}

// ---------------------------------------------------------------- BatchNorm
template <int M>
__global__ __launch_bounds__(256) void bn_stats(const float* __restrict__ H,
                                                float* __restrict__ sums, int N) {
    int tid = threadIdx.x;
    int c0 = (tid * 4) % M;
    float s[4] = {0.f, 0.f, 0.f, 0.f}, q[4] = {0.f, 0.f, 0.f, 0.f};
    const float4* H4 = (const float4*)H;
    int total4 = N * (M / 4);
    for (int i = blockIdx.x * 256 + tid; i < total4; i += 256 * gridDim.x) {
        float4 v = H4[i];
        s[0] += v.x; q[0] += v.x * v.x;
        s[1] += v.y; q[1] += v.y * v.y;
        s[2] += v.z; q[2] += v.z * v.z;
        s[3] += v.w; q[3] += v.w * v.w;
    }
    __shared__ float red[256 * 8];
    for (int j = 0; j < 4; j++) {
        red[tid * 8 + j] = s[j];
        red[tid * 8 + 4 + j] = q[j];
    }
    __syncthreads();
    constexpr int GRP = M / 4;
    if (tid < GRP) {
        float rs[8] = {0.f, 0.f, 0.f, 0.f, 0.f, 0.f, 0.f, 0.f};
        for (int p = tid; p < 256; p += GRP)
            for (int j = 0; j < 8; j++) rs[j] += red[p * 8 + j];
        for (int j = 0; j < 4; j++) {
            atomicAdd(&sums[c0 + j], rs[j]);
            atomicAdd(&sums[M + c0 + j], rs[4 + j]);
        }
    }
}

// layer-1 apply (finalize folded): fp32 in -> BN+ReLU -> bf16 out
__global__ __launch_bounds__(256) void bn_apply_bf128(const float* __restrict__ H,
                                                      const float* __restrict__ sums,
                                                      const float* __restrict__ gamma,
                                                      const float* __restrict__ beta,
                                                      unsigned short* __restrict__ O,
                                                      int N, float invN) {
    __shared__ float ss[256];
    int tid = threadIdx.x;
    if (tid < 128) {
        float mu = sums[tid] * invN;
        float var = sums[128 + tid] * invN - mu * mu;
        float sc = gamma[tid] * rsqrtf(var + EPS_BN);
        ss[tid] = sc;
        ss[128 + tid] = beta[tid] - mu * sc;
    }
    __syncthreads();
    int total4 = N * 32;
    const float4* H4 = (const float4*)H;
    for (int i = blockIdx.x * 256 + tid; i < total4; i += 256 * gridDim.x) {
        int c0 = (i * 4) & 127;
        float4 v = H4[i];
        float4 sc = *(const float4*)&ss[c0];
        float4 sh = *(const float4*)&ss[128 + c0];
        ushort4 o;
        o.x = f2bf(fmaxf(v.x * sc.x + sh.x, 0.f));
        o.y = f2bf(fmaxf(v.y * sc.y + sh.y, 0.f));
        o.z = f2bf(fmaxf(v.z * sc.z + sh.z, 0.f));
        o.w = f2bf(fmaxf(v.w * sc.w + sh.w, 0.f));
        *(ushort4*)&O[(size_t)i * 4] = o;
    }
}

// layer-2 apply (finalize folded): fp32 in-place, no ReLU
__global__ __launch_bounds__(256) void bn_apply_f64(float* H, const float* __restrict__ sums,
                                                    const float* __restrict__ gamma,
                                                    const float* __restrict__ beta,
                                                    int N, float invN) {
    __shared__ float ss[128];
    int tid = threadIdx.x;
    if (tid < 64) {
        float mu = sums[tid] * invN;
        float var = sums[64 + tid] * invN - mu * mu;
        float sc = gamma[tid] * rsqrtf(var + EPS_BN);
        ss[tid] = sc;
        ss[64 + tid] = beta[tid] - mu * sc;
    }
    __syncthreads();
    int total4 = N * 16;
    float4* H4 = (float4*)H;
    for (int i = blockIdx.x * 256 + tid; i < total4; i += 256 * gridDim.x) {
        int c0 = (i * 4) & 63;
        float4 v = H4[i];
        float4 sc = *(const float4*)&ss[c0];
        float4 sh = *(const float4*)&ss[64 + c0];
        v.x = v.x * sc.x + sh.x;
        v.y = v.y * sc.y + sh.y;
        v.z = v.z * sc.z + sh.z;
        v.w = v.w * sc.w + sh.w;
        H4[i] = v;
    }
}

// ---------------------------------------------------------------- launch
extern "C" void kernel_launch(void* const* d_in, const int* in_sizes, int n_in,
                              void* d_out, int out_size, void* d_ws, size_t ws_size,
                              hipStream_t stream) {
    const float* X = (const float*)d_in[0];
    const int* src = (const int*)d_in[1];
    const int* dst = (const int*)d_in[2];
    const float* Wself1 = (const float*)d_in[3];
    const float* Wneigh1 = (const float*)d_in[4];
    const float* b1 = (const float*)d_in[5];
    const float* g1 = (const float*)d_in[6];
    const float* be1 = (const float*)d_in[7];
    const float* Wself2 = (const float*)d_in[8];
    const float* Wneigh2 = (const float*)d_in[9];
    const float* b2 = (const float*)d_in[10];
    const float* g2 = (const float*)d_in[11];
    const float* be2 = (const float*)d_in[12];
    float* out = (float*)d_out;

    const int N = in_sizes[0] / 128;
    const int E = in_sizes[1];
    const int NB = (N + BINW - 1) >> BINSHIFT;    // 196
    const int NBLK = (E + P_EPB - 1) / P_EPB;     // 196

    char* p = (char*)d_ws;
    auto carve = [&](size_t bytes) {
        char* r = p;
        p += (bytes + 255) & ~(size_t)255;
        return r;
    };
    float* sums1 = (float*)carve(256 * 4);
    float* sums2 = (float*)carve(128 * 4);
    size_t zero_bytes = (size_t)(p - (char*)d_ws);
    int* counts = (int*)carve((size_t)NBLK * NB * 4);
    int* segbase = (int*)carve((size_t)NBLK * NB * 4);
    int* binBase = (int*)carve((size_t)(NB + 1) * 4);
    uint2* pairs = (uint2*)carve((size_t)E * 8);
    int* csr_src = (int*)carve((size_t)E * 4);
    int* row_start = (int*)carve((size_t)N * 4);
    int* cntg = (int*)carve((size_t)N * 4);
    float* inv_deg = (float*)carve((size_t)N * 4);
    unsigned short* W1f = (unsigned short*)carve(128 * 256 * 2);
    unsigned short* W2f = (unsigned short*)carve(128 * 128 * 2);
    float* bufA = (float*)carve((size_t)N * 128 * 4);
    unsigned short* Xb = (unsigned short*)carve((size_t)N * 128 * 2);   // also h1b
    unsigned short* tab = (unsigned short*)carve((size_t)N * 128 * 2);  // tab1/tab2

    hipMemsetAsync(d_ws, 0, zero_bytes, stream);

    const int cvtB = 1024, wB = 192;
    prep_kernel<<<cvtB + wB + NBLK, 256, 0, stream>>>(X, Xb, N * 32, Wself1, Wneigh1,
                                                      Wself2, Wneigh2, W1f, W2f, dst,
                                                      counts, E, NB, cvtB, wB);
    p2_scan<<<1, 512, 0, stream>>>(counts, segbase, binBase, NB, NBLK);
    p3_scatter<<<NBLK, 512, 0, stream>>>(src, dst, segbase, pairs, E, NB);
    p4_csr<<<NB, 512, 0, stream>>>(pairs, binBase, row_start, cntg, inv_deg, csr_src, N);

    int ggrid = (N + 63) / 64;
    // ---- layer 1 (128 -> 128)
    gemm_dual<256, 128><<<ggrid, 256, 0, stream>>>(Xb, W1f, bufA, tab, N);
    agg_bf128<<<(N + 3) / 4, 256, 0, stream>>>(bufA, (const unsigned int*)tab, row_start,
                                               cntg, inv_deg, csr_src, b1, bufA, N);
    bn_stats<128><<<256, 256, 0, stream>>>(bufA, sums1, N);
    bn_apply_bf128<<<2048, 256, 0, stream>>>(bufA, sums1, g1, be1, Xb, N, 1.0f / (float)N);

    // ---- layer 2 (128 -> 64)
    gemm_dual<128, 64><<<ggrid, 256, 0, stream>>>(Xb, W2f, out, tab, N);
    agg_bf64<<<(N + 3) / 4, 256, 0, stream>>>(out, tab, row_start, cntg, inv_deg, csr_src,
                                              b2, out, N);
    bn_stats<64><<<256, 256, 0, stream>>>(out, sums2, N);
    bn_apply_f64<<<2048, 256, 0, stream>>>(out, sums2, g2, be2, N, 1.0f / (float)N);
}